// Round 1
// baseline (1173.900 us; speedup 1.0000x reference)
//
#include <hip/hip_runtime.h>

// 2-layer stacked LSTM: B=256, T=2048, H=64, layer2 hidden=1.
// One block per batch element (256 blocks = 256 CUs), 320 threads (5 waves).
// Waves 0-3: layer 1. Wave w, lane l owns unit u = 16w + (l&15), gate g = l>>4.
// Wave 4: layer 2, 2-stage software pipeline.
// ONE __syncthreads per step (publishes h1 for the next step).
//
// Round-4 changes (theory: per-step barrier was draining a 4B global store via
// vmcnt(0), and the h1 broadcast was 64x ds_read_b128/step serializing on the
// single per-CU LDS pipe):
//  (A) h2 outputs buffered in LDS, bulk float4 store after the loop. The
//      in-loop __syncthreads now has vmcnt trivially 0 -> no store drain.
//  (B) h1 broadcast via ONE lane-distinct ds_read_b32 + v_readlane -> SGPR,
//      consumed as the scalar operand of v_fmac_f32. Moves the broadcast off
//      the shared LDS pipe onto per-SIMD VALU/SALU (4x more slack).
constexpr int kT = 2048;
constexpr int kB = 256;
constexpr int kH = 64;

__device__ __forceinline__ float fast_sig(float x) {
    return __builtin_amdgcn_rcpf(1.0f + __expf(-x));
}
__device__ __forceinline__ float fast_tanh(float x) {
    float t = __expf(2.0f * x);
    return 1.0f - 2.0f * __builtin_amdgcn_rcpf(t + 1.0f);
}
// Uniform broadcast of lane `lane`'s value to all lanes, via SGPR.
__device__ __forceinline__ float bcast(float v, int lane) {
    return __int_as_float(__builtin_amdgcn_readlane(__float_as_int(v), lane));
}

__global__ __launch_bounds__(320)
__attribute__((amdgpu_waves_per_eu(1)))
void lstm2_kernel(
    const float* __restrict__ x, const float* __restrict__ W1,
    const float* __restrict__ b1, const float* __restrict__ W2,
    const float* __restrict__ b2, float* __restrict__ out)
{
    __shared__ float4 x4_lds[kT / 4];     // whole input row (float4-aligned)
    __shared__ float4 out4_lds[kT / 4];   // h2 output staging (float4-aligned)
    __shared__ float h1_lds[2][kH];       // double-buffered h1
    float* x_lds = (float*)x4_lds;
    float* out_lds = (float*)out4_lds;

    const int tid = threadIdx.x;
    const int b = blockIdx.x;
    const float4* xg4 = (const float4*)(x + (size_t)b * kT);
    float4* outg4 = (float4*)(out + (size_t)b * kT);

    for (int i = tid; i < kT / 4; i += 320) x4_lds[i] = xg4[i];
    if (tid < kH) { h1_lds[0][tid] = 0.0f; h1_lds[1][tid] = 0.0f; }

    const int w = tid >> 6;   // wave id 0..4
    const int l = tid & 63;   // lane

    // ---- layer-1 per-lane state (waves 0-3): column weights in registers ----
    // wh4[k].{x,y,z,w} pairs with h1[4k+0 .. 4k+3] (W1 row j+1 multiplies h[j]).
    float w0 = 0.0f, b1g = 0.0f;
    float4 wh4[16];
    #pragma unroll
    for (int k = 0; k < 16; ++k) wh4[k] = make_float4(0.f, 0.f, 0.f, 0.f);
    float c1 = 0.0f;
    int u = 0, g = 0;

    // ---- layer-2 per-lane state (wave 4) ----
    float w2p0 = 0, w2p1 = 0, w2p2 = 0, w2p3 = 0;
    float4 w2t = {0, 0, 0, 0}, b2v = {0, 0, 0, 0};
    float c2 = 0.0f, h2 = 0.0f;
    float zi_s = 0, zj_s = 0, zf_s = 0, zo_s = 0;   // staged pre-activations

    if (w < 4) {
        g = l >> 4;
        u = 16 * w + (l & 15);
        const int col = g * 64 + u;      // gate-major columns: i,j,f,o blocks
        w0 = W1[col];
        b1g = b1[col];
        #pragma unroll
        for (int k = 0; k < 16; ++k) {
            wh4[k].x = W1[(4 * k + 1) * 256 + col];
            wh4[k].y = W1[(4 * k + 2) * 256 + col];
            wh4[k].z = W1[(4 * k + 3) * 256 + col];
            wh4[k].w = W1[(4 * k + 4) * 256 + col];
        }
    } else {
        const int s = l & 15, gg = l >> 4;       // slice, gate
        w2p0 = W2[(s +  0) * 4 + gg];
        w2p1 = W2[(s + 16) * 4 + gg];
        w2p2 = W2[(s + 32) * 4 + gg];
        w2p3 = W2[(s + 48) * 4 + gg];
        w2t = ((const float4*)W2)[kH];   // W2[64][0..3] (h2 recurrent row)
        b2v = ((const float4*)b2)[0];
    }

    // ---- PIN loop-invariant weights: opaque RMW stops rematerialization ----
    #pragma unroll
    for (int k = 0; k < 16; ++k)
        asm volatile("" : "+v"(wh4[k].x), "+v"(wh4[k].y),
                          "+v"(wh4[k].z), "+v"(wh4[k].w));
    asm volatile("" : "+v"(w0), "+v"(b1g));
    asm volatile("" : "+v"(w2p0), "+v"(w2p1), "+v"(w2p2), "+v"(w2p3));
    asm volatile("" : "+v"(w2t.x), "+v"(w2t.y), "+v"(w2t.z), "+v"(w2t.w));
    asm volatile("" : "+v"(b2v.x), "+v"(b2v.y), "+v"(b2v.z), "+v"(b2v.w));

    __syncthreads();

    int cur = 0;
    for (int t = 0; t < kT; ++t) {
        const int nxt = cur ^ 1;
        if (w < 4) {
            // ---- layer-1 step t: z = [x_t, h1(t-1)] . W1col + b ----
            const float xt = x_lds[t];
            const float hv = h1_lds[cur][l];  // ONE lane-distinct b32 read
            float z0 = fmaf(xt, w0, b1g), z1 = 0.0f, z2 = 0.0f, z3 = 0.0f;
            #pragma unroll
            for (int k = 0; k < 16; ++k) {
                z0 = fmaf(bcast(hv, 4 * k + 0), wh4[k].x, z0);
                z1 = fmaf(bcast(hv, 4 * k + 1), wh4[k].y, z1);
                z2 = fmaf(bcast(hv, 4 * k + 2), wh4[k].z, z2);
                z3 = fmaf(bcast(hv, 4 * k + 3), wh4[k].w, z3);
            }
            float z = (z0 + z1) + (z2 + z3);
            // g==1 -> tanh(z) = 2*sig(2z)-1; g==2 -> sig(z+1); else sig(z)
            float zz = (g == 1) ? 2.0f * z : ((g == 2) ? z + 1.0f : z);
            float sg = fast_sig(zz);
            float a = (g == 1) ? fmaf(2.0f, sg, -1.0f) : sg;
            // gather the 4 gates of unit u (all in this wave)
            const int base = l & 15;
            const float ai = __shfl(a, base);
            const float aj = __shfl(a, base + 16);
            const float af = __shfl(a, base + 32);
            const float ao = __shfl(a, base + 48);
            c1 = fmaf(af, c1, ai * aj);               // redundant in 4 lanes
            const float h1n = ao * fast_tanh(c1);
            if (g == 0) h1_lds[nxt][u] = h1n;
        } else {
            // ---- stage B: recurrent update for step t-2 (uses staged z) ----
            if (t >= 2) {
                const float zi = zi_s + h2 * w2t.x;
                const float zj = zj_s + h2 * w2t.y;
                const float zf = zf_s + h2 * w2t.z;
                const float zo = zo_s + h2 * w2t.w;
                c2 = fast_sig(zf + 1.0f) * c2 + fast_sig(zi) * fast_tanh(zj);
                h2 = fast_sig(zo) * fast_tanh(c2);
                if (l == 0) out_lds[t - 2] = h2;      // LDS, not global!
            }
            // ---- stage A: dot products for step t-1 (h1(t-1)=h1_lds[cur]) --
            if (t >= 1) {
                const int s = l & 15;
                const float* hb = h1_lds[cur];
                float p = hb[s] * w2p0;
                p = fmaf(hb[s + 16], w2p1, p);
                p = fmaf(hb[s + 32], w2p2, p);
                p = fmaf(hb[s + 48], w2p3, p);
                p += __shfl_xor(p, 1);
                p += __shfl_xor(p, 2);
                p += __shfl_xor(p, 4);
                p += __shfl_xor(p, 8);
                zi_s = __shfl(p, s)      + b2v.x;
                zj_s = __shfl(p, s + 16) + b2v.y;
                zf_s = __shfl(p, s + 32) + b2v.z;
                zo_s = __shfl(p, s + 48) + b2v.w;
            }
        }
        __syncthreads();
        cur = nxt;
    }

    // ---- epilogue (wave 4): finish steps T-2 and T-1 into LDS ----
    if (w == 4) {
        {
            const float zi = zi_s + h2 * w2t.x;
            const float zj = zj_s + h2 * w2t.y;
            const float zf = zf_s + h2 * w2t.z;
            const float zo = zo_s + h2 * w2t.w;
            c2 = fast_sig(zf + 1.0f) * c2 + fast_sig(zi) * fast_tanh(zj);
            h2 = fast_sig(zo) * fast_tanh(c2);
            if (l == 0) out_lds[kT - 2] = h2;
        }
        {
            const int s = l & 15;
            const float* hb = h1_lds[cur];
            float p = hb[s] * w2p0;
            p = fmaf(hb[s + 16], w2p1, p);
            p = fmaf(hb[s + 32], w2p2, p);
            p = fmaf(hb[s + 48], w2p3, p);
            p += __shfl_xor(p, 1);
            p += __shfl_xor(p, 2);
            p += __shfl_xor(p, 4);
            p += __shfl_xor(p, 8);
            const float zi = __shfl(p, s)      + b2v.x + h2 * w2t.x;
            const float zj = __shfl(p, s + 16) + b2v.y + h2 * w2t.y;
            const float zf = __shfl(p, s + 32) + b2v.z + h2 * w2t.z;
            const float zo = __shfl(p, s + 48) + b2v.w + h2 * w2t.w;
            c2 = fast_sig(zf + 1.0f) * c2 + fast_sig(zi) * fast_tanh(zj);
            h2 = fast_sig(zo) * fast_tanh(c2);
            if (l == 0) out_lds[kT - 1] = h2;
        }
    }

    // ---- bulk coalesced store of the whole output row ----
    __syncthreads();
    for (int i = tid; i < kT / 4; i += 320) outg4[i] = out4_lds[i];
}

extern "C" void kernel_launch(void* const* d_in, const int* in_sizes, int n_in,
                              void* d_out, int out_size, void* d_ws, size_t ws_size,
                              hipStream_t stream) {
    const float* x  = (const float*)d_in[0];
    const float* W1 = (const float*)d_in[1];
    const float* b1 = (const float*)d_in[2];
    const float* W2 = (const float*)d_in[3];
    const float* b2 = (const float*)d_in[4];
    float* out = (float*)d_out;
    lstm2_kernel<<<kB, 320, 0, stream>>>(x, W1, b1, W2, b2, out);
}